// Round 16
// baseline (110.499 us; speedup 1.0000x reference)
//
#include <hip/hip_runtime.h>
#include <hip/hip_bf16.h>
#include <math.h>

#define B_ 2
#define S_ 2048
#define D_ 1024
#define H_ 16
#define HD_ 64
#define M_ (B_*S_)          // 4096 rows
#define C1_ 0.1803368798f   // HD^-0.5 * log2(e)

typedef float f32x4 __attribute__((ext_vector_type(4)));
typedef float f32x16 __attribute__((ext_vector_type(16)));
typedef short s16x8 __attribute__((ext_vector_type(8)));

__device__ __forceinline__ short f2bf(float f) {
  union { float f; unsigned u; } x; x.f = f;
  unsigned r = x.u + 0x7fffu + ((x.u >> 16) & 1u);   // RNE
  return (short)(r >> 16);
}
__device__ __forceinline__ float bf2f(short v) {
  union { unsigned u; float f; } x; x.u = ((unsigned)(unsigned short)v) << 16;
  return x.f;
}
__device__ __forceinline__ unsigned cvt_pk_bf16(float a, float b) {
  unsigned r;
  asm("v_cvt_pk_bf16_f32 %0, %1, %2" : "=v"(r) : "v"(a), "v"(b));
  return r;
}
__device__ __forceinline__ float exp2_fast(float x) {
#if __has_builtin(__builtin_amdgcn_exp2f)
  return __builtin_amdgcn_exp2f(x);
#else
  float r; asm("v_exp_f32 %0, %1" : "=v"(r) : "v"(x)); return r;
#endif
}
__device__ __forceinline__ void gload_lds16(const void* g, void* l) {
  __builtin_amdgcn_global_load_lds(
      (const __attribute__((address_space(1))) void*)g,
      (__attribute__((address_space(3))) void*)l, 16, 0, 0);
}

// ---------------- fused prep: 4x weight transpose-cvt + query cvt ----------------
__global__ __launch_bounds__(256) void k_prep(
    const float* __restrict__ query, short* __restrict__ xbf,
    const float* __restrict__ W0, const float* __restrict__ W1,
    const float* __restrict__ W2, const float* __restrict__ W3,
    short* __restrict__ T0, short* __restrict__ T1,
    short* __restrict__ T2, short* __restrict__ T3) {
  __shared__ short lt[64][72];     // [col][row], padded
  const int blk = blockIdx.x;
  const int t = threadIdx.x;
  if (blk < 1024) {
    const int z = blk >> 8, tile = blk & 255;
    const float* W = z == 0 ? W0 : z == 1 ? W1 : z == 2 ? W2 : W3;
    short* Wt      = z == 0 ? T0 : z == 1 ? T1 : z == 2 ? T2 : T3;
    const int r0 = (tile >> 4) * 64;  // k rows
    const int c0 = (tile & 15) * 64;  // n cols
    const int rr = t >> 4, c4 = (t & 15) * 4;
    #pragma unroll
    for (int p = 0; p < 4; ++p) {
      int row = p * 16 + rr;
      f32x4 v = *reinterpret_cast<const f32x4*>(W + (size_t)(r0 + row) * D_ + c0 + c4);
      #pragma unroll
      for (int j = 0; j < 4; ++j) lt[c4 + j][row] = f2bf(v[j]);
    }
    __syncthreads();
    #pragma unroll
    for (int p = 0; p < 2; ++p) {
      int slot = p * 256 + t;
      int row = slot >> 3, s = slot & 7;
      s16x8 v = *reinterpret_cast<const s16x8*>(&lt[row][s * 8]);
      *reinterpret_cast<s16x8*>(Wt + (size_t)(c0 + row) * D_ + r0 + s * 8) = v;
    }
  } else {
    int i = ((blk - 1024) * 256 + t) * 8;
    f32x4 a = *reinterpret_cast<const f32x4*>(query + i);
    f32x4 b = *reinterpret_cast<const f32x4*>(query + i + 4);
    s16x8 v;
    v[0]=f2bf(a[0]); v[1]=f2bf(a[1]); v[2]=f2bf(a[2]); v[3]=f2bf(a[3]);
    v[4]=f2bf(b[0]); v[5]=f2bf(b[1]); v[6]=f2bf(b[2]); v[7]=f2bf(b[3]);
    *reinterpret_cast<s16x8*>(xbf + i) = v;
  }
}

// ---------------- fused QKV GEMM: 128x128 tile, 2-PHASE double-buffered LDS ----
// z=0: Q (bf16, pre-scaled by C1_), z=1: K (bf16), z=2: V (bf16 TRANSPOSED [D][M])
__global__ __launch_bounds__(256) void k_gemm_qkv(
    const short* __restrict__ A,
    const short* __restrict__ WtQ, const short* __restrict__ WtK, const short* __restrict__ WtV,
    const float* __restrict__ bQ, const float* __restrict__ bK, const float* __restrict__ bV,
    short* __restrict__ Qo, short* __restrict__ Ko, short* __restrict__ Vto) {
  __shared__ __align__(16) char lds[65536];
  const int z = blockIdx.z;
  const short* Bt   = z == 0 ? WtQ : z == 1 ? WtK : WtV;
  const float* bias = z == 0 ? bQ  : z == 1 ? bK  : bV;
  const int t = threadIdx.x;
  const int lane = t & 63, wid = t >> 6;
  const int l15 = lane & 15, l4 = lane >> 4;
  const int wm = wid >> 1, wn = wid & 1;
  const int m0 = blockIdx.x * 128, n0 = blockIdx.y * 128;

  f32x4 acc[4][4];
  #pragma unroll
  for (int i = 0; i < 4; ++i)
    #pragma unroll
    for (int j = 0; j < 4; ++j) acc[i][j] = (f32x4){0.f, 0.f, 0.f, 0.f};

  auto stage = [&](int k0, int buf) {
    char* base = lds + buf * 32768;
    #pragma unroll
    for (int i = 0; i < 4; ++i) {
      int slot = t + i * 256;
      int row = slot >> 3, sw = (t & 7) ^ (row & 7);
      gload_lds16(A  + (size_t)(m0 + row) * D_ + k0 + sw * 8, base + (i * 256 + wid * 64) * 16);
      gload_lds16(Bt + (size_t)(n0 + row) * D_ + k0 + sw * 8, base + 16384 + (i * 256 + wid * 64) * 16);
    }
  };

  stage(0, 0);
  __syncthreads();

  int buf = 0;
  for (int k0 = 0; k0 < D_; k0 += 64, buf ^= 1) {
    if (k0 + 64 < D_) stage(k0 + 64, buf ^ 1);   // issue next-tile loads FIRST (T3)
    const char* bA = lds + buf * 32768;
    const char* bB = bA + 16384;
    #pragma unroll
    for (int ks = 0; ks < 2; ++ks) {
      s16x8 af[4], bf[4];
      #pragma unroll
      for (int mt = 0; mt < 4; ++mt) {
        int row = wm * 64 + mt * 16 + l15;
        af[mt] = *reinterpret_cast<const s16x8*>(bA + row * 128 + (((ks*4 + l4) ^ (row & 7)) * 16));
      }
      #pragma unroll
      for (int nt = 0; nt < 4; ++nt) {
        int row = wn * 64 + nt * 16 + l15;
        bf[nt] = *reinterpret_cast<const s16x8*>(bB + row * 128 + (((ks*4 + l4) ^ (row & 7)) * 16));
      }
      #pragma unroll
      for (int mt = 0; mt < 4; ++mt)
        #pragma unroll
        for (int nt = 0; nt < 4; ++nt)
          acc[mt][nt] = __builtin_amdgcn_mfma_f32_16x16x32_bf16(af[mt], bf[nt], acc[mt][nt], 0, 0, 0);
    }
    __syncthreads();
  }

  const float scale = (z == 0) ? C1_ : 1.f;
  #pragma unroll
  for (int nt = 0; nt < 4; ++nt) {
    int cl = wn * 64 + nt * 16 + l15;
    float bv = bias[n0 + cl];
    #pragma unroll
    for (int mt = 0; mt < 4; ++mt) {
      #pragma unroll
      for (int r = 0; r < 4; ++r) {
        int rl = wm * 64 + mt * 16 + l4 * 4 + r;
        short hv = f2bf((acc[mt][nt][r] + bv) * scale);
        if (z == 2) *reinterpret_cast<short*>(lds + cl * 256 + rl * 2) = hv;
        else        *reinterpret_cast<short*>(lds + rl * 256 + cl * 2) = hv;
      }
    }
  }
  __syncthreads();
  short* outp = (z == 0) ? Qo : (z == 1) ? Ko : Vto;
  const size_t ld   = (z == 2) ? (size_t)M_ : (size_t)D_;
  const int rowbase = (z == 2) ? n0 : m0;
  const int colbase = (z == 2) ? m0 : n0;
  #pragma unroll
  for (int p = 0; p < 8; ++p) {
    int slot = p * 256 + t;
    int row = slot >> 4, s = slot & 15;
    s16x8 v = *reinterpret_cast<const s16x8*>(lds + row * 256 + s * 16);
    *reinterpret_cast<s16x8*>(outp + (size_t)(rowbase + row) * ld + colbase + s * 8) = v;
  }
}

// ---------------- Wo GEMM: 128x64 tile, 2-PHASE double-buffered LDS ----------------
__global__ __launch_bounds__(256) void k_gemm_out(const short* __restrict__ A,
                                                  const short* __restrict__ Bt,
                                                  const float* __restrict__ bias,
                                                  float* __restrict__ C) {
  __shared__ __align__(16) char lds[49152];
  const int t = threadIdx.x;
  const int lane = t & 63, wid = t >> 6;
  const int l15 = lane & 15, l4 = lane >> 4;
  const int wm = wid >> 1, wn = wid & 1;
  const int m0 = blockIdx.x * 128, n0 = blockIdx.y * 64;

  f32x4 acc[4][2];
  #pragma unroll
  for (int i = 0; i < 4; ++i)
    #pragma unroll
    for (int j = 0; j < 2; ++j) acc[i][j] = (f32x4){0.f, 0.f, 0.f, 0.f};

  auto stage = [&](int k0, int buf) {
    char* base = lds + buf * 24576;
    #pragma unroll
    for (int i = 0; i < 4; ++i) {
      int slot = t + i * 256;
      int row = slot >> 3, sw = (t & 7) ^ (row & 7);
      gload_lds16(A + (size_t)(m0 + row) * D_ + k0 + sw * 8, base + (i * 256 + wid * 64) * 16);
    }
    #pragma unroll
    for (int i = 0; i < 2; ++i) {
      int slot = t + i * 256;
      int row = slot >> 3, sw = (t & 7) ^ (row & 7);
      gload_lds16(Bt + (size_t)(n0 + row) * D_ + k0 + sw * 8,
                  base + 16384 + (i * 256 + wid * 64) * 16);
    }
  };

  stage(0, 0);
  __syncthreads();

  int buf = 0;
  for (int k0 = 0; k0 < D_; k0 += 64, buf ^= 1) {
    if (k0 + 64 < D_) stage(k0 + 64, buf ^ 1);
    const char* bA = lds + buf * 24576;
    const char* bB = bA + 16384;
    #pragma unroll
    for (int ks = 0; ks < 2; ++ks) {
      s16x8 af[4], bf[2];
      #pragma unroll
      for (int mt = 0; mt < 4; ++mt) {
        int row = wm * 64 + mt * 16 + l15;
        af[mt] = *reinterpret_cast<const s16x8*>(bA + row * 128 + (((ks*4 + l4) ^ (row & 7)) * 16));
      }
      #pragma unroll
      for (int nt = 0; nt < 2; ++nt) {
        int row = wn * 32 + nt * 16 + l15;
        bf[nt] = *reinterpret_cast<const s16x8*>(bB + row * 128 + (((ks*4 + l4) ^ (row & 7)) * 16));
      }
      #pragma unroll
      for (int mt = 0; mt < 4; ++mt)
        #pragma unroll
        for (int nt = 0; nt < 2; ++nt)
          acc[mt][nt] = __builtin_amdgcn_mfma_f32_16x16x32_bf16(af[mt], bf[nt], acc[mt][nt], 0, 0, 0);
    }
    __syncthreads();
  }
  #pragma unroll
  for (int nt = 0; nt < 2; ++nt) {
    int col = n0 + wn * 32 + nt * 16 + l15;
    float bv = bias[col];
    #pragma unroll
    for (int mt = 0; mt < 4; ++mt) {
      int row0 = m0 + wm * 64 + mt * 16 + l4 * 4;
      #pragma unroll
      for (int r = 0; r < 4; ++r)
        C[(size_t)(row0 + r) * D_ + col] = acc[mt][nt][r] + bv;
    }
  }
}

// ---------------- flash attention: intra-wave pipelined QK(t+1) || softmax(t) ----
// 256-thread blocks (4 waves), 32 q/wave. K staged 2 tiles ahead (4-buffer),
// V 1 ahead (2-buffer); scores double-buffered in registers. No-max softmax.
// Grid 32bh x 16qblk(128q) x NSPLIT, XCD-swizzled. Writes U partial + per-q l.
template <int NSPLIT>
__global__ __launch_bounds__(256, 2) void k_attn(const short* __restrict__ Q,
                                                 const short* __restrict__ K,
                                                 const short* __restrict__ Vt,
                                                 short* __restrict__ UA,
                                                 short* __restrict__ UB,
                                                 short* __restrict__ UC,
                                                 short* __restrict__ UD,
                                                 float* __restrict__ lsum) {
  // K: 4 x 8KB @ [0,32768)   V: 2 x 8KB @ [32768,49152)
  __shared__ __align__(16) char lds[49152];
  const int t = threadIdx.x;
  const int lane = t & 63, wid = t >> 6;               // wid 0..3
  const int l31 = lane & 31, hi = lane >> 5;
  const int orig = blockIdx.x;
  const int xcd = orig & 7, idx = orig >> 3;           // 4*16*NSPLIT blocks per XCD
  const int bh = xcd * 4 + idx / (16 * NSPLIT);
  const int rem = idx % (16 * NSPLIT);
  const int qblk = rem / NSPLIT;                       // 16 q-blocks of 128
  const int split = rem % NSPLIT;
  const int b = bh >> 4, h = bh & 15;
  const int q0 = qblk * 128;
  const size_t qkbase = (size_t)b * S_ * D_ + h * HD_;
  const short* gK = K + qkbase + (size_t)(split * (S_ / NSPLIT)) * D_;
  const short* gVt = Vt + (size_t)(h * HD_) * M_ + (size_t)b * S_ + split * (S_ / NSPLIT);
  short* Up = (split == 0) ? UA : (split == 1) ? UB : (split == 2) ? UC : UD;
  const int TILES = (S_ / 64) / NSPLIT;                // 16 (N=2) or 8 (N=4)

  // Q B-frags: B[k=d][col=q=l31], d = ks*16 + hi*8 + i
  s16x8 qf[4];
  {
    const short* qp = Q + qkbase + (size_t)(q0 + wid * 32 + l31) * D_ + hi * 8;
    #pragma unroll
    for (int ks = 0; ks < 4; ++ks)
      qf[ks] = *reinterpret_cast<const s16x8*>(qp + ks * 16);
  }

  f32x16 oa[2];                    // U[q=(reg&3)+8*(reg>>2)+4hi][d=dblk*32+l31]
  #pragma unroll
  for (int i = 0; i < 16; ++i) { oa[0][i] = 0.f; oa[1][i] = 0.f; }
  float lAcc = 0.f;

  // staging invariants (pre-swizzled global sources, linear LDS dest)
  const int tr3 = t >> 3;
  const int ssw8 = ((t & 7) ^ (tr3 & 7)) * 8;
  const size_t kSrc = (size_t)tr3 * D_ + ssw8;
  const size_t vSrc = (size_t)tr3 * M_ + ssw8;

  const int s7 = l31 & 7;
  const int rbase = l31 * 128;
  int soff[4];
  #pragma unroll
  for (int ks = 0; ks < 4; ++ks) soff[ks] = ((2 * ks + hi) ^ s7) * 16;

  auto stage_K = [&](int tl, int kb) {
    if (tl >= TILES) return;
    const short* pk = gK + (size_t)(tl * 64) * D_ + kSrc;
    char* dK = lds + kb * 8192 + wid * 1024;
    gload_lds16(pk, dK);
    gload_lds16(pk + (size_t)32 * D_, dK + 4096);
  };
  auto stage_V = [&](int tl, int vb) {
    if (tl >= TILES) return;
    const short* pv = gVt + tl * 64 + vSrc;
    char* dV = lds + 32768 + vb * 8192 + wid * 1024;
    gload_lds16(pv, dV);
    gload_lds16(pv + (size_t)32 * M_, dV + 4096);
  };

  auto qk_step = [&](int kb, f32x16* sc) {
    __builtin_amdgcn_s_setprio(1);
    #pragma unroll
    for (int ks = 0; ks < 4; ++ks)
      #pragma unroll
      for (int blk = 0; blk < 2; ++blk) {
        s16x8 kf = *reinterpret_cast<const s16x8*>(lds + kb * 8192 + blk * 4096 + rbase + soff[ks]);
        sc[blk] = __builtin_amdgcn_mfma_f32_32x32x16_bf16(kf, qf[ks], sc[blk], 0, 0, 0);
      }
    __builtin_amdgcn_s_setprio(0);
  };

  auto sm_pv = [&](f32x16* sc, int vb) {
    float rs = 0.f;
    unsigned p1[2][4], p2[2][4];
    #pragma unroll
    for (int blk = 0; blk < 2; ++blk)
      #pragma unroll
      for (int g = 0; g < 4; ++g) {
        float a0 = exp2_fast(sc[blk][4*g+0]), a1 = exp2_fast(sc[blk][4*g+1]);
        float a2 = exp2_fast(sc[blk][4*g+2]), a3 = exp2_fast(sc[blk][4*g+3]);
        rs += (a0 + a1) + (a2 + a3);
        p1[blk][g] = cvt_pk_bf16(a0, a1);
        p2[blk][g] = cvt_pk_bf16(a2, a3);
      }
    rs += __shfl_xor(rs, 32);
    lAcc += rs;
    __builtin_amdgcn_s_setprio(1);
    #pragma unroll
    for (int sp = 0; sp < 4; ++sp) {
      const int blk = sp >> 1, su = sp & 1;
      unsigned x0 = p1[blk][2*su],     x1 = p2[blk][2*su];
      unsigned y0 = p1[blk][2*su + 1], y1 = p2[blk][2*su + 1];
      asm("v_permlane32_swap_b32 %0, %1" : "+v"(x0), "+v"(y0));
      asm("v_permlane32_swap_b32 %0, %1" : "+v"(x1), "+v"(y1));
      union { unsigned u[4]; s16x8 v; } pw;
      pw.u[0] = x0; pw.u[1] = x1; pw.u[2] = y0; pw.u[3] = y1;
      #pragma unroll
      for (int dblk = 0; dblk < 2; ++dblk) {
        s16x8 vf = *reinterpret_cast<const s16x8*>(
            lds + 32768 + vb * 8192 + dblk * 4096 + rbase + soff[sp]);
        oa[dblk] = __builtin_amdgcn_mfma_f32_32x32x16_bf16(pw.v, vf, oa[dblk], 0, 0, 0);
      }
    }
    __builtin_amdgcn_s_setprio(0);
  };

  // prologue: K(0),V(0),K(1) staged; QK(0) computed
  stage_K(0, 0);
  stage_V(0, 0);
  stage_K(1, 1);
  __syncthreads();
  f32x16 scA[2], scB[2];
  #pragma unroll
  for (int i = 0; i < 16; ++i) { scA[0][i] = 0.f; scA[1][i] = 0.f; }
  qk_step(0, scA);

  #pragma unroll 1
  for (int it = 0; it < TILES; it += 2) {
    // even step: pending = scA, next -> scB
    #pragma unroll
    for (int i = 0; i < 16; ++i) { scB[0][i] = 0.f; scB[1][i] = 0.f; }
    if (it + 1 < TILES) qk_step((it + 1) & 3, scB);   // QK(t+1) first (indep)
    stage_K(it + 2, (it + 2) & 3);
    stage_V(it + 1, (it + 1) & 1);
    sm_pv(scA, it & 1);                               // softmax(t)+PV(t)
    __syncthreads();
    // odd step: pending = scB, next -> scA
    #pragma unroll
    for (int i = 0; i < 16; ++i) { scA[0][i] = 0.f; scA[1][i] = 0.f; }
    if (it + 2 < TILES) qk_step((it + 2) & 3, scA);
    stage_K(it + 3, (it + 3) & 3);
    stage_V(it + 2, (it + 2) & 1);
    sm_pv(scB, (it + 1) & 1);
    __syncthreads();
  }

  // epilogue: per-wave LDS repack (4KB/wave; staging regions free) + 16B stores
  char* myl = lds + wid * 4096;
  #pragma unroll
  for (int reg = 0; reg < 16; ++reg) {
    int qrow = (reg & 3) + 8 * (reg >> 2) + 4 * hi;
    *reinterpret_cast<short*>(myl + qrow * 128 + l31 * 2)        = f2bf(oa[0][reg]);
    *reinterpret_cast<short*>(myl + qrow * 128 + (32 + l31) * 2) = f2bf(oa[1][reg]);
  }
  #pragma unroll
  for (int i = 0; i < 4; ++i) {
    int slot = i * 64 + lane;
    int row = slot >> 3, s = slot & 7;
    s16x8 v = *reinterpret_cast<const s16x8*>(myl + slot * 16);
    *reinterpret_cast<s16x8*>(
        Up + qkbase + (size_t)(q0 + wid * 32 + row) * D_ + s * 8) = v;
  }
  if (hi == 0)
    lsum[((split * 32 + bh) << 11) + q0 + wid * 32 + l31] = lAcc;
}

// ---------------- merge NSPLIT kv-partials: O = sum(U) / sum(l) ----------------
template <int NSPLIT>
__global__ __launch_bounds__(256) void k_merge(const short* U0, const short* U1,
                                               const short* U2, const short* U3,
                                               const float* lsum, short* out) {
  int i = (blockIdx.x * 256 + threadIdx.x) * 8;        // over M_*D_
  int row = i >> 10;             // b*2048 + s
  int col = i & 1023;            // h*64 + hd
  int b = row >> 11, s = row & 2047;
  int bh = b * 16 + (col >> 6);
  float lt = 0.f;
  #pragma unroll
  for (int sp = 0; sp < NSPLIT; ++sp) lt += lsum[((sp * 32 + bh) << 11) + s];
  float inv = 1.f / lt;
  float acc[8];
  s16x8 u0 = *reinterpret_cast<const s16x8*>(U0 + i);
  s16x8 u1 = *reinterpret_cast<const s16x8*>(U1 + i);
  #pragma unroll
  for (int j = 0; j < 8; ++j) acc[j] = bf2f(u0[j]) + bf2f(u1[j]);
  if (NSPLIT == 4) {
    s16x8 u2 = *reinterpret_cast<const s16x8*>(U2 + i);
    s16x8 u3 = *reinterpret_cast<const s16x8*>(U3 + i);
    #pragma unroll
    for (int j = 0; j < 8; ++j) acc[j] += bf2f(u2[j]) + bf2f(u3[j]);
  }
  s16x8 r;
  #pragma unroll
  for (int j = 0; j < 8; ++j) r[j] = f2bf(acc[j] * inv);
  *reinterpret_cast<s16x8*>(out + i) = r;
}

extern "C" void kernel_launch(void* const* d_in, const int* in_sizes, int n_in,
                              void* d_out, int out_size, void* d_ws, size_t ws_size,
                              hipStream_t stream) {
  const float* query = (const float*)d_in[0];
  const float* Wq = (const float*)d_in[1];
  const float* bq = (const float*)d_in[2];
  const float* Wk = (const float*)d_in[3];
  const float* bk = (const float*)d_in[4];
  const float* Wv = (const float*)d_in[5];
  const float* bv = (const float*)d_in[6];
  const float* Wo = (const float*)d_in[7];
  const float* bo = (const float*)d_in[8];
  float* out = (float*)d_out;

  const size_t NE = (size_t)M_ * D_;
  short* ws   = (short*)d_ws;
  short* xbf  = ws;                            // query bf16; REUSED as U1 after QKV
  short* qbf  = ws + NE;                       // Q (pre-scaled by C1_)
  short* kbf  = ws + 2 * NE;
  short* vtbf = ws + 3 * NE;                   // V transposed [D][M]
  short* aout = ws + 4 * NE;                   // U0, then merged attention out (bf16)
  short* wtq  = ws + 5 * NE;                   // REUSED as lsum after QKV
  short* wtk  = wtq + (size_t)D_ * D_;
  short* wtv  = wtk + (size_t)D_ * D_;
  short* wto  = wtv + (size_t)D_ * D_;
  short* U2   = ws + 6 * NE;                   // only if ws permits (NSPLIT=4)
  short* U3   = ws + 7 * NE;

  short* U0 = aout;
  short* U1 = xbf;
  float* lsb = (float*)wtq;                    // 1 MB << D_*D_ shorts

  const bool split4 = ws_size >= (size_t)8 * NE * sizeof(short);  // 64 MB

  k_prep<<<3072, 256, 0, stream>>>(query, xbf, Wq, Wk, Wv, Wo, wtq, wtk, wtv, wto);

  k_gemm_qkv<<<dim3(M_ / 128, D_ / 128, 3), 256, 0, stream>>>(
      xbf, wtq, wtk, wtv, bq, bk, bv, qbf, kbf, vtbf);

  if (split4) {
    k_attn<4><<<2048, 256, 0, stream>>>(qbf, kbf, vtbf, U0, U1, U2, U3, lsb);
    k_merge<4><<<(int)(NE / (8 * 256)), 256, 0, stream>>>(U0, U1, U2, U3, lsb, aout);
  } else {
    k_attn<2><<<1024, 256, 0, stream>>>(qbf, kbf, vtbf, U0, U1, U0, U1, lsb);
    k_merge<2><<<(int)(NE / (8 * 256)), 256, 0, stream>>>(U0, U1, U0, U1, lsb, aout);
  }

  k_gemm_out<<<dim3(M_ / 128, D_ / 64), 256, 0, stream>>>(aout, wto, bo, out);
}